// Round 3
// baseline (413.971 us; speedup 1.0000x reference)
//
#include <hip/hip_runtime.h>

// Problem: x (512,3,224,224) f32; W (1,768) f32; b (1,) f32; P=16.
// out[b*196 + o/768] = bias + sum_k W[o%768]*A'[...]; A'[u] within a (b,p1)
// slab of 9408 elems: u = p2*588 + c*196 + h*14 + w, x col = 16w+p2, row = 16h+p1.
constexpr int CHW     = 150528;   // 3*224*224
constexpr int CPLANE  = 50176;    // 224*224
constexpr int OUT_PB  = 196;
constexpr int BLOCK_O = 9408;     // 16*588
constexpr int NF4     = 2352;     // 9408/4

__global__ __launch_bounds__(512, 8)
void patch_score_kernel(const float* __restrict__ x,
                        const float* __restrict__ W,
                        const float* __restrict__ bias,
                        float* __restrict__ out) {
    __shared__ float lds[BLOCK_O];   // 37,632 B, NO pad -> 4 blocks/CU, 32 waves/CU

    const int b   = blockIdx.x >> 4;
    const int p1  = blockIdx.x & 15;
    const int tid = threadIdx.x;

    const float* __restrict__ xb = x + (size_t)b * CHW + p1 * 224;

    // ---- Phase 1: 2352 float4 loads, 4 per thread + tail (tid<304).
    // f -> seg = c*14+h (56 float4 per row), off within row.
    float4 r[4];
    int base[4];
#pragma unroll
    for (int i = 0; i < 4; ++i) {
        const int f   = tid + i * 512;
        const int seg = f / 56;
        const int off = f - seg * 56;
        const int c   = seg / 14;
        const int h   = seg - c * 14;
        r[i] = *(const float4*)(xb + c * CPLANE + h * 3584 + 4 * off);
        // ww = 4*off -> p2_0 = (off&3)*4, w = off>>2; elems e land at base+588*e
        base[i] = (off & 3) * 4 * 588 + c * 196 + h * 14 + (off >> 2);
    }
    float4 rt; int baset = 0;
    if (tid < 304) {
        const int f   = tid + 2048;
        const int seg = f / 56;
        const int off = f - seg * 56;
        const int c   = seg / 14;
        const int h   = seg - c * 14;
        rt = *(const float4*)(xb + c * CPLANE + h * 3584 + 4 * off);
        baset = (off & 3) * 4 * 588 + c * 196 + h * 14 + (off >> 2);
    }
#pragma unroll
    for (int i = 0; i < 4; ++i) {
        lds[base[i]]        = r[i].x;
        lds[base[i] + 588]  = r[i].y;
        lds[base[i] + 1176] = r[i].z;
        lds[base[i] + 1764] = r[i].w;
    }
    if (tid < 304) {
        lds[baset]        = rt.x;
        lds[baset + 588]  = rt.y;
        lds[baset + 1176] = rt.z;
        lds[baset + 1764] = rt.w;
    }
    __syncthreads();

    // ---- Phase 2: rows j with [j*768,(j+1)*768) overlapping [o_base, o_base+9408).
    const int lane = tid & 63;
    const int wv   = tid >> 6;          // 0..7

    float wreg[12];
#pragma unroll
    for (int i = 0; i < 12; ++i) wreg[i] = W[i * 64 + lane];
    const float bv = bias[0];

    const int o_base  = p1 * BLOCK_O;
    const int j_start = o_base / 768;
    const int j_end   = (o_base + BLOCK_O - 1) / 768;

    for (int j = j_start + wv; j <= j_end; j += 8) {
        const int kb = j * 768 - o_base;
        float acc = 0.0f;
        bool interior = (kb >= 0) && (kb <= BLOCK_O - 768);
        if (interior) {
            const float* p = &lds[kb + lane];
#pragma unroll
            for (int i = 0; i < 12; ++i) acc += p[i * 64] * wreg[i];
        } else {
#pragma unroll
            for (int i = 0; i < 12; ++i) {
                const int u = kb + i * 64 + lane;
                if (u >= 0 && u < BLOCK_O) acc += lds[u] * wreg[i];
            }
        }
#pragma unroll
        for (int off = 32; off > 0; off >>= 1)
            acc += __shfl_down(acc, off, 64);
        if (lane == 0) {
            float* dst = &out[b * OUT_PB + j];
            if (interior)           *dst = acc + bv;            // row fully ours
            else if (kb > 0)        atomicAdd(dst, acc + bv);   // start-owner adds bias
            else                    atomicAdd(dst, acc);        // end-owner
        }
    }
}

extern "C" void kernel_launch(void* const* d_in, const int* in_sizes, int n_in,
                              void* d_out, int out_size, void* d_ws, size_t ws_size,
                              hipStream_t stream) {
    const float* x    = (const float*)d_in[0];
    const float* W    = (const float*)d_in[1];
    const float* bias = (const float*)d_in[2];
    float* out = (float*)d_out;

    // Shared (block-boundary) rows are accumulated via atomicAdd -> need zeros.
    hipMemsetAsync(out, 0, (size_t)out_size * sizeof(float), stream);

    patch_score_kernel<<<512 * 16, 512, 0, stream>>>(x, W, bias, out);
}